// Round 1
// baseline (3902.398 us; speedup 1.0000x reference)
//
#include <hip/hip_runtime.h>

#define NN 50000
#define NE 800000
#define EPSV 1e-5f

// ---------------- degree ----------------
__global__ void deg_kernel(const int* __restrict__ dst, float* __restrict__ deg, int ne) {
    int e = blockIdx.x * blockDim.x + threadIdx.x;
    if (e < ne) unsafeAtomicAdd(&deg[dst[e]], 1.0f);
}

// ---------------- scatter-add: agg[dst] += x[src] ----------------
// F floats per node, F % 4 == 0. TPE = F/4 threads per edge, each does one float4.
template<int F>
__global__ void scatter_kernel(const float* __restrict__ x, const int* __restrict__ src,
                               const int* __restrict__ dst, float* __restrict__ agg, int ne) {
    constexpr int TPE = F / 4;
    long long tid = (long long)blockIdx.x * blockDim.x + threadIdx.x;
    int e = (int)(tid / TPE);
    if (e >= ne) return;
    int f = (int)(tid % TPE) * 4;
    int s = src[e], d = dst[e];
    float4 v = *reinterpret_cast<const float4*>(x + (size_t)s * F + f);
    float* o = agg + (size_t)d * F + f;
    unsafeAtomicAdd(o + 0, v.x);
    unsafeAtomicAdd(o + 1, v.y);
    unsafeAtomicAdd(o + 2, v.z);
    unsafeAtomicAdd(o + 3, v.w);
}

// ---------------- fused GEMM: y = (agg/deg)@Wagg + bias + x@Wroot, + BN col stats ----------------
// Block: 256 threads. Tile: ROWS rows x N cols. CG = N/4 col-groups, RT = 256/CG row-threads,
// RPT = ROWS/RT rows per thread (strided by RT).
template<int K, int N, int ROWS, bool HAS_AGG, bool BN>
__global__ __launch_bounds__(256) void gemm_kernel(
    const float* __restrict__ xin, const float* __restrict__ agg,
    const float* __restrict__ deg,
    const float* __restrict__ Wroot, const float* __restrict__ Wagg,
    const float* __restrict__ bias,
    float* __restrict__ y, float* __restrict__ stats, int M)
{
    constexpr int Kc  = 32;
    constexpr int CG  = N / 4;
    constexpr int RT  = 256 / CG;
    constexpr int RPT = ROWS / RT;
    constexpr int XP  = Kc + 4;   // padded LDS stride (dwords), keeps float4 alignment + breaks bank aliasing

    __shared__ float sWr[Kc * N];
    __shared__ float sWa[HAS_AGG ? Kc * N : 1];
    __shared__ float sX [ROWS * XP];
    __shared__ float sA [HAS_AGG ? ROWS * XP : 1];
    __shared__ float sStat[BN ? 2 * N : 1];

    const int tid  = threadIdx.x;
    const int tx   = tid % CG;      // col group
    const int ty   = tid / CG;      // row thread
    const int row0 = blockIdx.x * ROWS;

    float acc[RPT][4];
    #pragma unroll
    for (int i = 0; i < RPT; i++) { acc[i][0]=0.f; acc[i][1]=0.f; acc[i][2]=0.f; acc[i][3]=0.f; }

    for (int k0 = 0; k0 < K; k0 += Kc) {
        // stage W chunk (Kc x N) for both mats
        for (int idx = tid; idx < Kc * N / 4; idx += 256) {
            int r = (idx * 4) / N, c = (idx * 4) % N;
            *reinterpret_cast<float4*>(&sWr[r * N + c]) =
                *reinterpret_cast<const float4*>(&Wroot[(size_t)(k0 + r) * N + c]);
            if constexpr (HAS_AGG)
                *reinterpret_cast<float4*>(&sWa[r * N + c]) =
                    *reinterpret_cast<const float4*>(&Wagg[(size_t)(k0 + r) * N + c]);
        }
        // stage x / agg tile (ROWS x Kc), agg scaled by 1/max(deg,1)
        for (int idx = tid; idx < ROWS * Kc / 4; idx += 256) {
            int r = idx / (Kc / 4);
            int c = (idx % (Kc / 4)) * 4;
            int grow = row0 + r;
            float4 xv = make_float4(0.f, 0.f, 0.f, 0.f);
            float4 av = make_float4(0.f, 0.f, 0.f, 0.f);
            if (grow < M) {
                xv = *reinterpret_cast<const float4*>(&xin[(size_t)grow * K + k0 + c]);
                if constexpr (HAS_AGG) {
                    av = *reinterpret_cast<const float4*>(&agg[(size_t)grow * K + k0 + c]);
                    float inv = 1.0f / fmaxf(deg[grow], 1.0f);
                    av.x *= inv; av.y *= inv; av.z *= inv; av.w *= inv;
                }
            }
            *reinterpret_cast<float4*>(&sX[r * XP + c]) = xv;
            if constexpr (HAS_AGG) *reinterpret_cast<float4*>(&sA[r * XP + c]) = av;
        }
        __syncthreads();

        #pragma unroll
        for (int kk = 0; kk < Kc; kk++) {
            float4 wr = *reinterpret_cast<const float4*>(&sWr[kk * N + tx * 4]);
            float4 wa = make_float4(0.f, 0.f, 0.f, 0.f);
            if constexpr (HAS_AGG) wa = *reinterpret_cast<const float4*>(&sWa[kk * N + tx * 4]);
            #pragma unroll
            for (int i = 0; i < RPT; i++) {
                int r = ty + i * RT;
                float xv = sX[r * XP + kk];
                acc[i][0] = fmaf(xv, wr.x, acc[i][0]);
                acc[i][1] = fmaf(xv, wr.y, acc[i][1]);
                acc[i][2] = fmaf(xv, wr.z, acc[i][2]);
                acc[i][3] = fmaf(xv, wr.w, acc[i][3]);
                if constexpr (HAS_AGG) {
                    float av = sA[r * XP + kk];
                    acc[i][0] = fmaf(av, wa.x, acc[i][0]);
                    acc[i][1] = fmaf(av, wa.y, acc[i][1]);
                    acc[i][2] = fmaf(av, wa.z, acc[i][2]);
                    acc[i][3] = fmaf(av, wa.w, acc[i][3]);
                }
            }
        }
        __syncthreads();
    }

    float4 bv = *reinterpret_cast<const float4*>(&bias[tx * 4]);

    if constexpr (BN) {
        for (int idx = tid; idx < 2 * N; idx += 256) sStat[idx] = 0.f;
        __syncthreads();
    }

    float cs[4] = {0.f,0.f,0.f,0.f}, cq[4] = {0.f,0.f,0.f,0.f};
    #pragma unroll
    for (int i = 0; i < RPT; i++) {
        int grow = row0 + ty + i * RT;
        if (grow < M) {
            float4 o;
            o.x = acc[i][0] + bv.x;
            o.y = acc[i][1] + bv.y;
            o.z = acc[i][2] + bv.z;
            o.w = acc[i][3] + bv.w;
            *reinterpret_cast<float4*>(&y[(size_t)grow * N + tx * 4]) = o;
            if constexpr (BN) {
                cs[0] += o.x; cq[0] += o.x * o.x;
                cs[1] += o.y; cq[1] += o.y * o.y;
                cs[2] += o.z; cq[2] += o.z * o.z;
                cs[3] += o.w; cq[3] += o.w * o.w;
            }
        }
    }

    if constexpr (BN) {
        atomicAdd(&sStat[tx * 4 + 0], cs[0]);
        atomicAdd(&sStat[tx * 4 + 1], cs[1]);
        atomicAdd(&sStat[tx * 4 + 2], cs[2]);
        atomicAdd(&sStat[tx * 4 + 3], cs[3]);
        atomicAdd(&sStat[N + tx * 4 + 0], cq[0]);
        atomicAdd(&sStat[N + tx * 4 + 1], cq[1]);
        atomicAdd(&sStat[N + tx * 4 + 2], cq[2]);
        atomicAdd(&sStat[N + tx * 4 + 3], cq[3]);
        __syncthreads();
        for (int idx = tid; idx < 2 * N; idx += 256)
            unsafeAtomicAdd(&stats[idx], sStat[idx]);
    }
}

// ---------------- BN finalize: scale/shift per column ----------------
__global__ void bnfin_kernel(const float* __restrict__ stats, const float* __restrict__ g,
                             const float* __restrict__ be, float* __restrict__ ss,
                             int N, float invM) {
    int c = threadIdx.x;
    if (c >= N) return;
    float mean = stats[c] * invM;
    float var  = stats[N + c] * invM - mean * mean;
    float sc   = g[c] * rsqrtf(fmaxf(var, 0.f) + EPSV);
    ss[c]     = sc;
    ss[N + c] = be[c] - mean * sc;
}

// ---------------- normalize + ReLU (in place) ----------------
template<int N>
__global__ void normrelu_kernel(float* __restrict__ y, const float* __restrict__ ss, int M) {
    long long idx = (long long)blockIdx.x * blockDim.x + threadIdx.x;
    if (idx >= (long long)M * (N / 4)) return;
    int c = (int)((idx * 4) % N);
    float4 v = *reinterpret_cast<float4*>(&y[idx * 4]);
    float4 sc = *reinterpret_cast<const float4*>(&ss[c]);
    float4 sh = *reinterpret_cast<const float4*>(&ss[N + c]);
    v.x = fmaxf(fmaf(v.x, sc.x, sh.x), 0.f);
    v.y = fmaxf(fmaf(v.y, sc.y, sh.y), 0.f);
    v.z = fmaxf(fmaf(v.z, sc.z, sh.z), 0.f);
    v.w = fmaxf(fmaf(v.w, sc.w, sh.w), 0.f);
    *reinterpret_cast<float4*>(&y[idx * 4]) = v;
}

extern "C" void kernel_launch(void* const* d_in, const int* in_sizes, int n_in,
                              void* d_out, int out_size, void* d_ws, size_t ws_size,
                              hipStream_t stream) {
    const float* x   = (const float*)d_in[0];
    const int*   ei  = (const int*)d_in[1];
    const int*   src = ei;
    const int*   dst = ei + NE;
    const float *W1l = (const float*)d_in[2],  *b1 = (const float*)d_in[3],
                *W1r = (const float*)d_in[4],  *g1 = (const float*)d_in[5],  *be1 = (const float*)d_in[6];
    const float *W2l = (const float*)d_in[7],  *b2 = (const float*)d_in[8],
                *W2r = (const float*)d_in[9],  *g2 = (const float*)d_in[10], *be2 = (const float*)d_in[11];
    const float *W3l = (const float*)d_in[12], *b3 = (const float*)d_in[13],
                *W3r = (const float*)d_in[14], *g3 = (const float*)d_in[15], *be3 = (const float*)d_in[16];
    const float *Wp  = (const float*)d_in[17], *bp = (const float*)d_in[18];

    float* w = (float*)d_ws;
    size_t off = 0;
    float* deg   = w + off; off += 50048;            // padded
    float* stats = w + off; off += 1536;             // 512 per layer
    float* ss    = w + off; off += 1536;             // 512 per layer (scale | shift)
    size_t zero_elems = off + (size_t)NN * 128;      // deg+stats+ss+agg zeroed up-front
    float* agg   = w + off; off += (size_t)NN * 128; // reused per layer
    float* h1    = w + off; off += (size_t)NN * 64;
    float* h2    = w + off; off += (size_t)NN * 128;
    float* h3    = w + off; off += (size_t)NN * 256;

    hipMemsetAsync(d_ws, 0, zero_elems * sizeof(float), stream);

    // degree (shared by all layers)
    deg_kernel<<<(NE + 255) / 256, 256, 0, stream>>>(dst, deg, NE);

    // ---- layer 1: in 128 -> out 64 ----
    scatter_kernel<128><<<(NE * 32) / 256, 256, 0, stream>>>(x, src, dst, agg, NE);
    gemm_kernel<128, 64, 64, true, true><<<(NN + 63) / 64, 256, 0, stream>>>(
        x, agg, deg, W1r, W1l, b1, h1, stats + 0, NN);
    bnfin_kernel<<<1, 256, 0, stream>>>(stats + 0, g1, be1, ss + 0, 64, 1.0f / NN);
    normrelu_kernel<64><<<(NN * 16 + 255) / 256, 256, 0, stream>>>(h1, ss + 0, NN);

    // ---- layer 2: in 64 -> out 128 ----
    hipMemsetAsync(agg, 0, (size_t)NN * 64 * sizeof(float), stream);
    scatter_kernel<64><<<(NE * 16) / 256, 256, 0, stream>>>(h1, src, dst, agg, NE);
    gemm_kernel<64, 128, 64, true, true><<<(NN + 63) / 64, 256, 0, stream>>>(
        h1, agg, deg, W2r, W2l, b2, h2, stats + 512, NN);
    bnfin_kernel<<<1, 256, 0, stream>>>(stats + 512, g2, be2, ss + 512, 128, 1.0f / NN);
    normrelu_kernel<128><<<(NN * 32 + 255) / 256, 256, 0, stream>>>(h2, ss + 512, NN);

    // ---- layer 3: in 128 -> out 256 ----
    hipMemsetAsync(agg, 0, (size_t)NN * 128 * sizeof(float), stream);
    scatter_kernel<128><<<(NE * 32) / 256, 256, 0, stream>>>(h2, src, dst, agg, NE);
    gemm_kernel<128, 256, 32, true, true><<<(NN + 31) / 32, 256, 0, stream>>>(
        h2, agg, deg, W3r, W3l, b3, h3, stats + 1024, NN);
    bnfin_kernel<<<1, 256, 0, stream>>>(stats + 1024, g3, be3, ss + 1024, 256, 1.0f / NN);
    normrelu_kernel<256><<<(NN * 64 + 255) / 256, 256, 0, stream>>>(h3, ss + 1024, NN);

    // ---- projection: 256 -> 128, straight to d_out ----
    gemm_kernel<256, 128, 64, false, false><<<(NN + 63) / 64, 256, 0, stream>>>(
        h3, nullptr, nullptr, Wp, nullptr, bp, (float*)d_out, nullptr, NN);
}

// Round 5
// 720.883 us; speedup vs baseline: 5.4134x; 5.4134x over previous
//
#include <hip/hip_runtime.h>

#define NN 50000
#define NE 800000
#define NNP 50176           // NN padded to 196*256
#define EPSV 1e-5f

// ---------------- CSR build: histogram ----------------
__global__ void hist_kernel(const int* __restrict__ dst, int* __restrict__ cnt, int ne) {
    int e = blockIdx.x * blockDim.x + threadIdx.x;
    if (e < ne) atomicAdd(&cnt[dst[e]], 1);
}

// ---------------- CSR build: 3-phase exclusive scan over NNP elements ----------------
__global__ void scan1_kernel(const int* __restrict__ cnt, int* __restrict__ row_ptr,
                             int* __restrict__ bsum) {
    __shared__ int s[256];
    int i = blockIdx.x * 256 + threadIdx.x;
    int v = cnt[i];
    s[threadIdx.x] = v;
    __syncthreads();
    #pragma unroll
    for (int off = 1; off < 256; off <<= 1) {
        int t = (threadIdx.x >= off) ? s[threadIdx.x - off] : 0;
        __syncthreads();
        s[threadIdx.x] += t;
        __syncthreads();
    }
    row_ptr[i] = s[threadIdx.x] - v;           // exclusive within block
    if (threadIdx.x == 255) bsum[blockIdx.x] = s[255];
}

__global__ void scan2_kernel(int* __restrict__ bsum, int nb) {
    __shared__ int s[256];
    int v = (threadIdx.x < nb) ? bsum[threadIdx.x] : 0;
    s[threadIdx.x] = v;
    __syncthreads();
    #pragma unroll
    for (int off = 1; off < 256; off <<= 1) {
        int t = (threadIdx.x >= off) ? s[threadIdx.x - off] : 0;
        __syncthreads();
        s[threadIdx.x] += t;
        __syncthreads();
    }
    if (threadIdx.x < nb) bsum[threadIdx.x] = s[threadIdx.x] - v;  // exclusive
}

__global__ void scan3_kernel(int* __restrict__ row_ptr, const int* __restrict__ bsum,
                             int* __restrict__ fill) {
    int i = blockIdx.x * 256 + threadIdx.x;
    int v = row_ptr[i] + bsum[blockIdx.x];
    row_ptr[i] = v;
    if (i < NN) fill[i] = v;   // running insert cursors start at row offsets
}

// ---------------- CSR build: bucket fill ----------------
__global__ void fill_kernel(const int* __restrict__ src, const int* __restrict__ dst,
                            int* __restrict__ fill, int* __restrict__ eidx, int ne) {
    int e = blockIdx.x * blockDim.x + threadIdx.x;
    if (e >= ne) return;
    int pos = atomicAdd(&fill[dst[e]], 1);
    eidx[pos] = src[e];
}

// ---------------- gather mean-aggregation: agg[n] = mean_{s in adj(n)} x[s] ----------------
// TPN = F/4 lanes per node, each owns one float4 column slice.
template<int F>
__global__ __launch_bounds__(256) void gather_kernel(
    const float* __restrict__ x, const int* __restrict__ row_ptr,
    const int* __restrict__ eidx, float* __restrict__ agg) {
    constexpr int TPN = F / 4;
    constexpr int NPB = 256 / TPN;
    int t = threadIdx.x;
    int node = blockIdx.x * NPB + t / TPN;
    if (node >= NN) return;
    int f = (t % TPN) * 4;
    int beg = row_ptr[node], end = row_ptr[node + 1];
    float4 acc = make_float4(0.f, 0.f, 0.f, 0.f);
    for (int i = beg; i < end; i++) {
        int s = eidx[i];
        float4 v = *reinterpret_cast<const float4*>(x + (size_t)s * F + f);
        acc.x += v.x; acc.y += v.y; acc.z += v.z; acc.w += v.w;
    }
    float inv = 1.0f / (float)max(end - beg, 1);
    acc.x *= inv; acc.y *= inv; acc.z *= inv; acc.w *= inv;
    *reinterpret_cast<float4*>(agg + (size_t)node * F + f) = acc;
}

// ---------------- fused GEMM: y = agg@Wagg + bias + x@Wroot, + BN col stats ----------------
// agg is already the mean (pre-divided by gather).
template<int K, int N, int ROWS, bool HAS_AGG, bool BN>
__global__ __launch_bounds__(256) void gemm_kernel(
    const float* __restrict__ xin, const float* __restrict__ agg,
    const float* __restrict__ Wroot, const float* __restrict__ Wagg,
    const float* __restrict__ bias,
    float* __restrict__ y, float* __restrict__ stats, int M)
{
    constexpr int Kc  = 32;
    constexpr int CG  = N / 4;
    constexpr int RT  = 256 / CG;
    constexpr int RPT = ROWS / RT;
    constexpr int XP  = Kc + 4;

    __shared__ float sWr[Kc * N];
    __shared__ float sWa[HAS_AGG ? Kc * N : 1];
    __shared__ float sX [ROWS * XP];
    __shared__ float sA [HAS_AGG ? ROWS * XP : 1];
    __shared__ float sStat[BN ? 2 * N : 1];

    const int tid  = threadIdx.x;
    const int tx   = tid % CG;
    const int ty   = tid / CG;
    const int row0 = blockIdx.x * ROWS;

    float acc[RPT][4];
    #pragma unroll
    for (int i = 0; i < RPT; i++) { acc[i][0]=0.f; acc[i][1]=0.f; acc[i][2]=0.f; acc[i][3]=0.f; }

    for (int k0 = 0; k0 < K; k0 += Kc) {
        for (int idx = tid; idx < Kc * N / 4; idx += 256) {
            int r = (idx * 4) / N, c = (idx * 4) % N;
            *reinterpret_cast<float4*>(&sWr[r * N + c]) =
                *reinterpret_cast<const float4*>(&Wroot[(size_t)(k0 + r) * N + c]);
            if constexpr (HAS_AGG)
                *reinterpret_cast<float4*>(&sWa[r * N + c]) =
                    *reinterpret_cast<const float4*>(&Wagg[(size_t)(k0 + r) * N + c]);
        }
        for (int idx = tid; idx < ROWS * Kc / 4; idx += 256) {
            int r = idx / (Kc / 4);
            int c = (idx % (Kc / 4)) * 4;
            int grow = row0 + r;
            float4 xv = make_float4(0.f, 0.f, 0.f, 0.f);
            float4 av = make_float4(0.f, 0.f, 0.f, 0.f);
            if (grow < M) {
                xv = *reinterpret_cast<const float4*>(&xin[(size_t)grow * K + k0 + c]);
                if constexpr (HAS_AGG)
                    av = *reinterpret_cast<const float4*>(&agg[(size_t)grow * K + k0 + c]);
            }
            *reinterpret_cast<float4*>(&sX[r * XP + c]) = xv;
            if constexpr (HAS_AGG) *reinterpret_cast<float4*>(&sA[r * XP + c]) = av;
        }
        __syncthreads();

        #pragma unroll
        for (int kk = 0; kk < Kc; kk++) {
            float4 wr = *reinterpret_cast<const float4*>(&sWr[kk * N + tx * 4]);
            float4 wa = make_float4(0.f, 0.f, 0.f, 0.f);
            if constexpr (HAS_AGG) wa = *reinterpret_cast<const float4*>(&sWa[kk * N + tx * 4]);
            #pragma unroll
            for (int i = 0; i < RPT; i++) {
                int r = ty + i * RT;
                float xv = sX[r * XP + kk];
                acc[i][0] = fmaf(xv, wr.x, acc[i][0]);
                acc[i][1] = fmaf(xv, wr.y, acc[i][1]);
                acc[i][2] = fmaf(xv, wr.z, acc[i][2]);
                acc[i][3] = fmaf(xv, wr.w, acc[i][3]);
                if constexpr (HAS_AGG) {
                    float av = sA[r * XP + kk];
                    acc[i][0] = fmaf(av, wa.x, acc[i][0]);
                    acc[i][1] = fmaf(av, wa.y, acc[i][1]);
                    acc[i][2] = fmaf(av, wa.z, acc[i][2]);
                    acc[i][3] = fmaf(av, wa.w, acc[i][3]);
                }
            }
        }
        __syncthreads();
    }

    float4 bv = *reinterpret_cast<const float4*>(&bias[tx * 4]);

    if constexpr (BN) {
        for (int idx = tid; idx < 2 * N; idx += 256) sStat[idx] = 0.f;
        __syncthreads();
    }

    float cs[4] = {0.f,0.f,0.f,0.f}, cq[4] = {0.f,0.f,0.f,0.f};
    #pragma unroll
    for (int i = 0; i < RPT; i++) {
        int grow = row0 + ty + i * RT;
        if (grow < M) {
            float4 o;
            o.x = acc[i][0] + bv.x;
            o.y = acc[i][1] + bv.y;
            o.z = acc[i][2] + bv.z;
            o.w = acc[i][3] + bv.w;
            *reinterpret_cast<float4*>(&y[(size_t)grow * N + tx * 4]) = o;
            if constexpr (BN) {
                cs[0] += o.x; cq[0] += o.x * o.x;
                cs[1] += o.y; cq[1] += o.y * o.y;
                cs[2] += o.z; cq[2] += o.z * o.z;
                cs[3] += o.w; cq[3] += o.w * o.w;
            }
        }
    }

    if constexpr (BN) {
        atomicAdd(&sStat[tx * 4 + 0], cs[0]);
        atomicAdd(&sStat[tx * 4 + 1], cs[1]);
        atomicAdd(&sStat[tx * 4 + 2], cs[2]);
        atomicAdd(&sStat[tx * 4 + 3], cs[3]);
        atomicAdd(&sStat[N + tx * 4 + 0], cq[0]);
        atomicAdd(&sStat[N + tx * 4 + 1], cq[1]);
        atomicAdd(&sStat[N + tx * 4 + 2], cq[2]);
        atomicAdd(&sStat[N + tx * 4 + 3], cq[3]);
        __syncthreads();
        for (int idx = tid; idx < 2 * N; idx += 256)
            unsafeAtomicAdd(&stats[idx], sStat[idx]);
    }
}

// ---------------- BN finalize ----------------
__global__ void bnfin_kernel(const float* __restrict__ stats, const float* __restrict__ g,
                             const float* __restrict__ be, float* __restrict__ ss,
                             int N, float invM) {
    int c = threadIdx.x;
    if (c >= N) return;
    float mean = stats[c] * invM;
    float var  = stats[N + c] * invM - mean * mean;
    float sc   = g[c] * rsqrtf(fmaxf(var, 0.f) + EPSV);
    ss[c]     = sc;
    ss[N + c] = be[c] - mean * sc;
}

// ---------------- normalize + ReLU (in place) ----------------
template<int N>
__global__ void normrelu_kernel(float* __restrict__ y, const float* __restrict__ ss, int M) {
    long long idx = (long long)blockIdx.x * blockDim.x + threadIdx.x;
    if (idx >= (long long)M * (N / 4)) return;
    int c = (int)((idx * 4) % N);
    float4 v = *reinterpret_cast<float4*>(&y[idx * 4]);
    float4 sc = *reinterpret_cast<const float4*>(&ss[c]);
    float4 sh = *reinterpret_cast<const float4*>(&ss[N + c]);
    v.x = fmaxf(fmaf(v.x, sc.x, sh.x), 0.f);
    v.y = fmaxf(fmaf(v.y, sc.y, sh.y), 0.f);
    v.z = fmaxf(fmaf(v.z, sc.z, sh.z), 0.f);
    v.w = fmaxf(fmaf(v.w, sc.w, sh.w), 0.f);
    *reinterpret_cast<float4*>(&y[idx * 4]) = v;
}

extern "C" void kernel_launch(void* const* d_in, const int* in_sizes, int n_in,
                              void* d_out, int out_size, void* d_ws, size_t ws_size,
                              hipStream_t stream) {
    const float* x   = (const float*)d_in[0];
    const int*   ei  = (const int*)d_in[1];
    const int*   src = ei;
    const int*   dst = ei + NE;
    const float *W1l = (const float*)d_in[2],  *b1 = (const float*)d_in[3],
                *W1r = (const float*)d_in[4],  *g1 = (const float*)d_in[5],  *be1 = (const float*)d_in[6];
    const float *W2l = (const float*)d_in[7],  *b2 = (const float*)d_in[8],
                *W2r = (const float*)d_in[9],  *g2 = (const float*)d_in[10], *be2 = (const float*)d_in[11];
    const float *W3l = (const float*)d_in[12], *b3 = (const float*)d_in[13],
                *W3r = (const float*)d_in[14], *g3 = (const float*)d_in[15], *be3 = (const float*)d_in[16];
    const float *Wp  = (const float*)d_in[17], *bp = (const float*)d_in[18];

    char* w = (char*)d_ws;
    size_t off = 0;
    auto alloc = [&](size_t bytes) { char* p = w + off; off += (bytes + 255) & ~255ULL; return p; };

    int*   cnt     = (int*)  alloc(NNP * 4);          // zeroed
    float* stats   = (float*)alloc(1536 * 4);         // zeroed
    size_t zero_bytes = off;
    float* ss      = (float*)alloc(1536 * 4);
    int*   row_ptr = (int*)  alloc((NNP + 1) * 4);
    int*   fillc   = (int*)  alloc(NNP * 4);
    int*   bsum    = (int*)  alloc(256 * 4);
    int*   eidx    = (int*)  alloc((size_t)NE * 4);
    float* agg     = (float*)alloc((size_t)NN * 128 * 4);
    float* h1      = (float*)alloc((size_t)NN * 64 * 4);
    float* h2      = (float*)alloc((size_t)NN * 128 * 4);
    float* h3      = (float*)alloc((size_t)NN * 256 * 4);

    hipMemsetAsync(d_ws, 0, zero_bytes, stream);

    // ---- CSR build (once, reused by all 3 layers) ----
    hist_kernel<<<(NE + 255) / 256, 256, 0, stream>>>(dst, cnt, NE);
    scan1_kernel<<<NNP / 256, 256, 0, stream>>>(cnt, row_ptr, bsum);
    scan2_kernel<<<1, 256, 0, stream>>>(bsum, NNP / 256);
    scan3_kernel<<<NNP / 256, 256, 0, stream>>>(row_ptr, bsum, fillc);
    fill_kernel<<<(NE + 255) / 256, 256, 0, stream>>>(src, dst, fillc, eidx, NE);

    // ---- layer 1: in 128 -> out 64 ----
    gather_kernel<128><<<(NN * 32 + 255) / 256, 256, 0, stream>>>(x, row_ptr, eidx, agg);
    gemm_kernel<128, 64, 64, true, true><<<(NN + 63) / 64, 256, 0, stream>>>(
        x, agg, W1r, W1l, b1, h1, stats + 0, NN);
    bnfin_kernel<<<1, 256, 0, stream>>>(stats + 0, g1, be1, ss + 0, 64, 1.0f / NN);
    normrelu_kernel<64><<<(NN * 16 + 255) / 256, 256, 0, stream>>>(h1, ss + 0, NN);

    // ---- layer 2: in 64 -> out 128 ----
    gather_kernel<64><<<(NN * 16 + 255) / 256, 256, 0, stream>>>(h1, row_ptr, eidx, agg);
    gemm_kernel<64, 128, 64, true, true><<<(NN + 63) / 64, 256, 0, stream>>>(
        h1, agg, W2r, W2l, b2, h2, stats + 512, NN);
    bnfin_kernel<<<1, 256, 0, stream>>>(stats + 512, g2, be2, ss + 512, 128, 1.0f / NN);
    normrelu_kernel<128><<<(NN * 32 + 255) / 256, 256, 0, stream>>>(h2, ss + 512, NN);

    // ---- layer 3: in 128 -> out 256 ----
    gather_kernel<128><<<(NN * 32 + 255) / 256, 256, 0, stream>>>(h2, row_ptr, eidx, agg);
    gemm_kernel<128, 256, 32, true, true><<<(NN + 31) / 32, 256, 0, stream>>>(
        h2, agg, W3r, W3l, b3, h3, stats + 1024, NN);
    bnfin_kernel<<<1, 256, 0, stream>>>(stats + 1024, g3, be3, ss + 1024, 256, 1.0f / NN);
    normrelu_kernel<256><<<(NN * 64 + 255) / 256, 256, 0, stream>>>(h3, ss + 1024, NN);

    // ---- projection: 256 -> 128, straight to d_out ----
    gemm_kernel<256, 128, 64, false, false><<<(NN + 63) / 64, 256, 0, stream>>>(
        h3, nullptr, Wp, nullptr, bp, (float*)d_out, nullptr, NN);
}

// Round 7
// 631.646 us; speedup vs baseline: 6.1781x; 1.1413x over previous
//
#include <hip/hip_runtime.h>

#define NN 50000
#define NE 800000
#define NNP 50176           // NN padded to 196*256
#define EPSV 1e-5f

// ---------------- CSR build: histogram ----------------
__global__ void hist_kernel(const int* __restrict__ dst, int* __restrict__ cnt, int ne) {
    int e = blockIdx.x * blockDim.x + threadIdx.x;
    if (e < ne) atomicAdd(&cnt[dst[e]], 1);
}

// ---------------- CSR build: 3-phase exclusive scan over NNP elements ----------------
__global__ void scan1_kernel(const int* __restrict__ cnt, int* __restrict__ row_ptr,
                             int* __restrict__ bsum) {
    __shared__ int s[256];
    int i = blockIdx.x * 256 + threadIdx.x;
    int v = cnt[i];
    s[threadIdx.x] = v;
    __syncthreads();
    #pragma unroll
    for (int off = 1; off < 256; off <<= 1) {
        int t = (threadIdx.x >= off) ? s[threadIdx.x - off] : 0;
        __syncthreads();
        s[threadIdx.x] += t;
        __syncthreads();
    }
    row_ptr[i] = s[threadIdx.x] - v;           // exclusive within block
    if (threadIdx.x == 255) bsum[blockIdx.x] = s[255];
}

__global__ void scan2_kernel(int* __restrict__ bsum, int nb) {
    __shared__ int s[256];
    int v = (threadIdx.x < nb) ? bsum[threadIdx.x] : 0;
    s[threadIdx.x] = v;
    __syncthreads();
    #pragma unroll
    for (int off = 1; off < 256; off <<= 1) {
        int t = (threadIdx.x >= off) ? s[threadIdx.x - off] : 0;
        __syncthreads();
        s[threadIdx.x] += t;
        __syncthreads();
    }
    if (threadIdx.x < nb) bsum[threadIdx.x] = s[threadIdx.x] - v;  // exclusive
}

__global__ void scan3_kernel(int* __restrict__ row_ptr, const int* __restrict__ bsum,
                             int* __restrict__ fill) {
    int i = blockIdx.x * 256 + threadIdx.x;
    int v = row_ptr[i] + bsum[blockIdx.x];
    row_ptr[i] = v;
    if (i < NN) fill[i] = v;   // running insert cursors start at row offsets
}

// ---------------- CSR build: bucket fill ----------------
__global__ void fill_kernel(const int* __restrict__ src, const int* __restrict__ dst,
                            int* __restrict__ fill, int* __restrict__ eidx, int ne) {
    int e = blockIdx.x * blockDim.x + threadIdx.x;
    if (e >= ne) return;
    int pos = atomicAdd(&fill[dst[e]], 1);
    eidx[pos] = src[e];
}

// ---------------- gather mean-aggregation ----------------
// agg[n] = mean_{s in adj(n)} act(x[s]) where act = relu(v*sc+sh) if AFF else identity.
// ss layout: [F scales | F shifts] of the layer that PRODUCED x.
template<int F, bool AFF>
__global__ __launch_bounds__(256) void gather_kernel(
    const float* __restrict__ x, const int* __restrict__ row_ptr,
    const int* __restrict__ eidx, float* __restrict__ agg,
    const float* __restrict__ ss) {
    constexpr int TPN = F / 4;
    constexpr int NPB = 256 / TPN;
    int t = threadIdx.x;
    int node = blockIdx.x * NPB + t / TPN;
    if (node >= NN) return;
    int f = (t % TPN) * 4;
    float4 sc = make_float4(1.f, 1.f, 1.f, 1.f);
    float4 sh = make_float4(0.f, 0.f, 0.f, 0.f);
    if constexpr (AFF) {
        sc = *reinterpret_cast<const float4*>(&ss[f]);
        sh = *reinterpret_cast<const float4*>(&ss[F + f]);
    }
    int beg = row_ptr[node], end = row_ptr[node + 1];
    float4 acc = make_float4(0.f, 0.f, 0.f, 0.f);
    for (int i = beg; i < end; i++) {
        int s = eidx[i];
        float4 v = *reinterpret_cast<const float4*>(x + (size_t)s * F + f);
        if constexpr (AFF) {
            v.x = fmaxf(fmaf(v.x, sc.x, sh.x), 0.f);
            v.y = fmaxf(fmaf(v.y, sc.y, sh.y), 0.f);
            v.z = fmaxf(fmaf(v.z, sc.z, sh.z), 0.f);
            v.w = fmaxf(fmaf(v.w, sc.w, sh.w), 0.f);
        }
        acc.x += v.x; acc.y += v.y; acc.z += v.z; acc.w += v.w;
    }
    float inv = 1.0f / (float)max(end - beg, 1);
    acc.x *= inv; acc.y *= inv; acc.z *= inv; acc.w *= inv;
    *reinterpret_cast<float4*>(agg + (size_t)node * F + f) = acc;
}

// ---------------- fused GEMM: y = agg@Wagg + bias + act(x)@Wroot, + BN col stats ----
// act applied to the root input during staging (AFFX); agg is already activated+meaned.
// Grid: (ceil(M/ROWS), N/NB). Each block computes ROWS x NB output columns [col0, col0+NB).
template<int K, int N, int NB, int ROWS, bool HAS_AGG, bool BN, bool AFFX>
__global__ __launch_bounds__(256, 4) void gemm_kernel(
    const float* __restrict__ xin, const float* __restrict__ agg,
    const float* __restrict__ Wroot, const float* __restrict__ Wagg,
    const float* __restrict__ bias, const float* __restrict__ ssx,
    float* __restrict__ y, float* __restrict__ stats, int M)
{
    constexpr int Kc  = 16;
    constexpr int CG  = NB / 4;         // col groups (threads in col dim)
    constexpr int RT  = 256 / CG;       // row threads
    constexpr int RPT = ROWS / RT;      // rows per thread
    constexpr int XP  = Kc + 4;         // padded LDS stride

    __shared__ float sWr[Kc * NB];
    __shared__ float sWa[HAS_AGG ? Kc * NB : 1];
    __shared__ float sX [ROWS * XP];
    __shared__ float sA [HAS_AGG ? ROWS * XP : 1];
    __shared__ float sStat[BN ? 2 * NB : 1];

    const int tid  = threadIdx.x;
    const int tx   = tid % CG;
    const int ty   = tid / CG;
    const int row0 = blockIdx.x * ROWS;
    const int col0 = blockIdx.y * NB;

    float acc[RPT][4];
    #pragma unroll
    for (int i = 0; i < RPT; i++) { acc[i][0]=0.f; acc[i][1]=0.f; acc[i][2]=0.f; acc[i][3]=0.f; }

    for (int k0 = 0; k0 < K; k0 += Kc) {
        // stage W chunk (Kc x NB) for both mats
        for (int idx = tid; idx < Kc * NB / 4; idx += 256) {
            int r = (idx * 4) / NB, c = (idx * 4) % NB;
            *reinterpret_cast<float4*>(&sWr[r * NB + c]) =
                *reinterpret_cast<const float4*>(&Wroot[(size_t)(k0 + r) * N + col0 + c]);
            if constexpr (HAS_AGG)
                *reinterpret_cast<float4*>(&sWa[r * NB + c]) =
                    *reinterpret_cast<const float4*>(&Wagg[(size_t)(k0 + r) * N + col0 + c]);
        }
        // stage x / agg tile (ROWS x Kc); apply producing-layer BN+ReLU to x if AFFX
        for (int idx = tid; idx < ROWS * Kc / 4; idx += 256) {
            int r = idx / (Kc / 4);
            int c = (idx % (Kc / 4)) * 4;
            int grow = row0 + r;
            float4 xv = make_float4(0.f, 0.f, 0.f, 0.f);
            float4 av = make_float4(0.f, 0.f, 0.f, 0.f);
            if (grow < M) {
                xv = *reinterpret_cast<const float4*>(&xin[(size_t)grow * K + k0 + c]);
                if constexpr (AFFX) {
                    float4 sc = *reinterpret_cast<const float4*>(&ssx[k0 + c]);
                    float4 sh = *reinterpret_cast<const float4*>(&ssx[K + k0 + c]);
                    xv.x = fmaxf(fmaf(xv.x, sc.x, sh.x), 0.f);
                    xv.y = fmaxf(fmaf(xv.y, sc.y, sh.y), 0.f);
                    xv.z = fmaxf(fmaf(xv.z, sc.z, sh.z), 0.f);
                    xv.w = fmaxf(fmaf(xv.w, sc.w, sh.w), 0.f);
                }
                if constexpr (HAS_AGG)
                    av = *reinterpret_cast<const float4*>(&agg[(size_t)grow * K + k0 + c]);
            }
            *reinterpret_cast<float4*>(&sX[r * XP + c]) = xv;
            if constexpr (HAS_AGG) *reinterpret_cast<float4*>(&sA[r * XP + c]) = av;
        }
        __syncthreads();

        #pragma unroll
        for (int kk = 0; kk < Kc; kk++) {
            float4 wr = *reinterpret_cast<const float4*>(&sWr[kk * NB + tx * 4]);
            float4 wa = make_float4(0.f, 0.f, 0.f, 0.f);
            if constexpr (HAS_AGG) wa = *reinterpret_cast<const float4*>(&sWa[kk * NB + tx * 4]);
            #pragma unroll
            for (int i = 0; i < RPT; i++) {
                int r = ty + i * RT;
                float xv = sX[r * XP + kk];
                acc[i][0] = fmaf(xv, wr.x, acc[i][0]);
                acc[i][1] = fmaf(xv, wr.y, acc[i][1]);
                acc[i][2] = fmaf(xv, wr.z, acc[i][2]);
                acc[i][3] = fmaf(xv, wr.w, acc[i][3]);
                if constexpr (HAS_AGG) {
                    float av = sA[r * XP + kk];
                    acc[i][0] = fmaf(av, wa.x, acc[i][0]);
                    acc[i][1] = fmaf(av, wa.y, acc[i][1]);
                    acc[i][2] = fmaf(av, wa.z, acc[i][2]);
                    acc[i][3] = fmaf(av, wa.w, acc[i][3]);
                }
            }
        }
        __syncthreads();
    }

    float4 bv = *reinterpret_cast<const float4*>(&bias[col0 + tx * 4]);

    if constexpr (BN) {
        for (int idx = tid; idx < 2 * NB; idx += 256) sStat[idx] = 0.f;
        __syncthreads();
    }

    float cs[4] = {0.f,0.f,0.f,0.f}, cq[4] = {0.f,0.f,0.f,0.f};
    #pragma unroll
    for (int i = 0; i < RPT; i++) {
        int grow = row0 + ty + i * RT;
        if (grow < M) {
            float4 o;
            o.x = acc[i][0] + bv.x;
            o.y = acc[i][1] + bv.y;
            o.z = acc[i][2] + bv.z;
            o.w = acc[i][3] + bv.w;
            *reinterpret_cast<float4*>(&y[(size_t)grow * N + col0 + tx * 4]) = o;
            if constexpr (BN) {
                cs[0] += o.x; cq[0] += o.x * o.x;
                cs[1] += o.y; cq[1] += o.y * o.y;
                cs[2] += o.z; cq[2] += o.z * o.z;
                cs[3] += o.w; cq[3] += o.w * o.w;
            }
        }
    }

    if constexpr (BN) {
        atomicAdd(&sStat[tx * 4 + 0], cs[0]);
        atomicAdd(&sStat[tx * 4 + 1], cs[1]);
        atomicAdd(&sStat[tx * 4 + 2], cs[2]);
        atomicAdd(&sStat[tx * 4 + 3], cs[3]);
        atomicAdd(&sStat[NB + tx * 4 + 0], cq[0]);
        atomicAdd(&sStat[NB + tx * 4 + 1], cq[1]);
        atomicAdd(&sStat[NB + tx * 4 + 2], cq[2]);
        atomicAdd(&sStat[NB + tx * 4 + 3], cq[3]);
        __syncthreads();
        for (int idx = tid; idx < 2 * NB; idx += 256) {
            int gidx = (idx < NB) ? (col0 + idx) : (N + col0 + idx - NB);
            unsafeAtomicAdd(&stats[gidx], sStat[idx]);
        }
    }
}

// ---------------- BN finalize: scale/shift per column ----------------
__global__ void bnfin_kernel(const float* __restrict__ stats, const float* __restrict__ g,
                             const float* __restrict__ be, float* __restrict__ ss,
                             int N, float invM) {
    int c = threadIdx.x;
    if (c >= N) return;
    float mean = stats[c] * invM;
    float var  = stats[N + c] * invM - mean * mean;
    float sc   = g[c] * rsqrtf(fmaxf(var, 0.f) + EPSV);
    ss[c]     = sc;
    ss[N + c] = be[c] - mean * sc;
}

extern "C" void kernel_launch(void* const* d_in, const int* in_sizes, int n_in,
                              void* d_out, int out_size, void* d_ws, size_t ws_size,
                              hipStream_t stream) {
    const float* x   = (const float*)d_in[0];
    const int*   ei  = (const int*)d_in[1];
    const int*   src = ei;
    const int*   dst = ei + NE;
    const float *W1l = (const float*)d_in[2],  *b1 = (const float*)d_in[3],
                *W1r = (const float*)d_in[4],  *g1 = (const float*)d_in[5],  *be1 = (const float*)d_in[6];
    const float *W2l = (const float*)d_in[7],  *b2 = (const float*)d_in[8],
                *W2r = (const float*)d_in[9],  *g2 = (const float*)d_in[10], *be2 = (const float*)d_in[11];
    const float *W3l = (const float*)d_in[12], *b3 = (const float*)d_in[13],
                *W3r = (const float*)d_in[14], *g3 = (const float*)d_in[15], *be3 = (const float*)d_in[16];
    const float *Wp  = (const float*)d_in[17], *bp = (const float*)d_in[18];

    char* w = (char*)d_ws;
    size_t off = 0;
    auto alloc = [&](size_t bytes) { char* p = w + off; off += (bytes + 255) & ~255ULL; return p; };

    int*   cnt     = (int*)  alloc(NNP * 4);          // zeroed
    float* stats   = (float*)alloc(1536 * 4);         // zeroed
    size_t zero_bytes = off;
    float* ss      = (float*)alloc(1536 * 4);
    int*   row_ptr = (int*)  alloc((NNP + 1) * 4);
    int*   fillc   = (int*)  alloc(NNP * 4);
    int*   bsum    = (int*)  alloc(256 * 4);
    int*   eidx    = (int*)  alloc((size_t)NE * 4);
    float* agg     = (float*)alloc((size_t)NN * 128 * 4);
    float* h1      = (float*)alloc((size_t)NN * 64 * 4);
    float* h2      = (float*)alloc((size_t)NN * 128 * 4);
    float* h3      = (float*)alloc((size_t)NN * 256 * 4);

    float* ss1 = ss + 0;     // [64 sc | 64 sh]
    float* ss2 = ss + 512;   // [128 sc | 128 sh]
    float* ss3 = ss + 1024;  // [256 sc | 256 sh]

    hipMemsetAsync(d_ws, 0, zero_bytes, stream);

    // ---- CSR build (once, reused by all 3 layers) ----
    hist_kernel<<<(NE + 255) / 256, 256, 0, stream>>>(dst, cnt, NE);
    scan1_kernel<<<NNP / 256, 256, 0, stream>>>(cnt, row_ptr, bsum);
    scan2_kernel<<<1, 256, 0, stream>>>(bsum, NNP / 256);
    scan3_kernel<<<NNP / 256, 256, 0, stream>>>(row_ptr, bsum, fillc);
    fill_kernel<<<(NE + 255) / 256, 256, 0, stream>>>(src, dst, fillc, eidx, NE);

    // ---- layer 1: in 128 -> out 64 (raw x, no activation) ----
    gather_kernel<128, false><<<(NN * 32 + 255) / 256, 256, 0, stream>>>(
        x, row_ptr, eidx, agg, nullptr);
    gemm_kernel<128, 64, 64, 64, true, true, false>
        <<<dim3((NN + 63) / 64, 1), 256, 0, stream>>>(
        x, agg, W1r, W1l, b1, nullptr, h1, stats + 0, NN);
    bnfin_kernel<<<1, 256, 0, stream>>>(stats + 0, g1, be1, ss1, 64, 1.0f / NN);

    // ---- layer 2: in 64 -> out 128 (h1 activated on the fly via ss1) ----
    gather_kernel<64, true><<<(NN * 16 + 255) / 256, 256, 0, stream>>>(
        h1, row_ptr, eidx, agg, ss1);
    gemm_kernel<64, 128, 128, 64, true, true, true>
        <<<dim3((NN + 63) / 64, 1), 256, 0, stream>>>(
        h1, agg, W2r, W2l, b2, ss1, h2, stats + 512, NN);
    bnfin_kernel<<<1, 256, 0, stream>>>(stats + 512, g2, be2, ss2, 128, 1.0f / NN);

    // ---- layer 3: in 128 -> out 256 (h2 activated via ss2; N split over 2 blocks) ----
    gather_kernel<128, true><<<(NN * 32 + 255) / 256, 256, 0, stream>>>(
        h2, row_ptr, eidx, agg, ss2);
    gemm_kernel<128, 256, 128, 64, true, true, true>
        <<<dim3((NN + 63) / 64, 2), 256, 0, stream>>>(
        h2, agg, W3r, W3l, b3, ss2, h3, stats + 1024, NN);
    bnfin_kernel<<<1, 256, 0, stream>>>(stats + 1024, g3, be3, ss3, 256, 1.0f / NN);

    // ---- projection: 256 -> 128 (h3 activated via ss3), straight to d_out ----
    gemm_kernel<256, 128, 128, 64, false, false, true>
        <<<dim3((NN + 63) / 64, 1), 256, 0, stream>>>(
        h3, nullptr, Wp, nullptr, bp, ss3, (float*)d_out, nullptr, NN);
}

// Round 9
// 608.571 us; speedup vs baseline: 6.4124x; 1.0379x over previous
//
#include <hip/hip_runtime.h>

#define NN 50000
#define NE 800000
#define NNP 50176           // NN padded to 196*256
#define EPSV 1e-5f

// ---------------- CSR build: histogram ----------------
__global__ void hist_kernel(const int* __restrict__ dst, int* __restrict__ cnt, int ne) {
    int e = blockIdx.x * blockDim.x + threadIdx.x;
    if (e < ne) atomicAdd(&cnt[dst[e]], 1);
}

// ---------------- CSR build: 3-phase exclusive scan over NNP elements ----------------
__global__ void scan1_kernel(const int* __restrict__ cnt, int* __restrict__ row_ptr,
                             int* __restrict__ bsum) {
    __shared__ int s[256];
    int i = blockIdx.x * 256 + threadIdx.x;
    int v = cnt[i];
    s[threadIdx.x] = v;
    __syncthreads();
    #pragma unroll
    for (int off = 1; off < 256; off <<= 1) {
        int t = (threadIdx.x >= off) ? s[threadIdx.x - off] : 0;
        __syncthreads();
        s[threadIdx.x] += t;
        __syncthreads();
    }
    row_ptr[i] = s[threadIdx.x] - v;           // exclusive within block
    if (threadIdx.x == 255) bsum[blockIdx.x] = s[255];
}

__global__ void scan2_kernel(int* __restrict__ bsum, int nb) {
    __shared__ int s[256];
    int v = (threadIdx.x < nb) ? bsum[threadIdx.x] : 0;
    s[threadIdx.x] = v;
    __syncthreads();
    #pragma unroll
    for (int off = 1; off < 256; off <<= 1) {
        int t = (threadIdx.x >= off) ? s[threadIdx.x - off] : 0;
        __syncthreads();
        s[threadIdx.x] += t;
        __syncthreads();
    }
    if (threadIdx.x < nb) bsum[threadIdx.x] = s[threadIdx.x] - v;  // exclusive
}

__global__ void scan3_kernel(int* __restrict__ row_ptr, const int* __restrict__ bsum,
                             int* __restrict__ fill) {
    int i = blockIdx.x * 256 + threadIdx.x;
    int v = row_ptr[i] + bsum[blockIdx.x];
    row_ptr[i] = v;
    if (i < NN) fill[i] = v;   // running insert cursors start at row offsets
}

// ---------------- CSR build: bucket fill ----------------
__global__ void fill_kernel(const int* __restrict__ src, const int* __restrict__ dst,
                            int* __restrict__ fill, int* __restrict__ eidx, int ne) {
    int e = blockIdx.x * blockDim.x + threadIdx.x;
    if (e >= ne) return;
    int pos = atomicAdd(&fill[dst[e]], 1);
    eidx[pos] = src[e];
}

// ---------------- gather mean-aggregation ----------------
// agg[n] = mean_{s in adj(n)} act(x[s]) where act = relu(v*sc+sh) if AFF else identity.
// ss layout: [F scales | F shifts] of the layer that PRODUCED x.
// Edge loop unrolled x2 with dual accumulators for memory-level parallelism.
template<int F, bool AFF>
__global__ __launch_bounds__(256) void gather_kernel(
    const float* __restrict__ x, const int* __restrict__ row_ptr,
    const int* __restrict__ eidx, float* __restrict__ agg,
    const float* __restrict__ ss) {
    constexpr int TPN = F / 4;
    constexpr int NPB = 256 / TPN;
    int t = threadIdx.x;
    int node = blockIdx.x * NPB + t / TPN;
    if (node >= NN) return;
    int f = (t % TPN) * 4;
    float4 sc = make_float4(1.f, 1.f, 1.f, 1.f);
    float4 sh = make_float4(0.f, 0.f, 0.f, 0.f);
    if constexpr (AFF) {
        sc = *reinterpret_cast<const float4*>(&ss[f]);
        sh = *reinterpret_cast<const float4*>(&ss[F + f]);
    }
    int beg = row_ptr[node], end = row_ptr[node + 1];
    float4 a0 = make_float4(0.f, 0.f, 0.f, 0.f);
    float4 a1 = make_float4(0.f, 0.f, 0.f, 0.f);
    int i = beg;
    for (; i + 1 < end; i += 2) {
        int s0 = eidx[i], s1 = eidx[i + 1];
        float4 v0 = *reinterpret_cast<const float4*>(x + (size_t)s0 * F + f);
        float4 v1 = *reinterpret_cast<const float4*>(x + (size_t)s1 * F + f);
        if constexpr (AFF) {
            v0.x = fmaxf(fmaf(v0.x, sc.x, sh.x), 0.f);
            v0.y = fmaxf(fmaf(v0.y, sc.y, sh.y), 0.f);
            v0.z = fmaxf(fmaf(v0.z, sc.z, sh.z), 0.f);
            v0.w = fmaxf(fmaf(v0.w, sc.w, sh.w), 0.f);
            v1.x = fmaxf(fmaf(v1.x, sc.x, sh.x), 0.f);
            v1.y = fmaxf(fmaf(v1.y, sc.y, sh.y), 0.f);
            v1.z = fmaxf(fmaf(v1.z, sc.z, sh.z), 0.f);
            v1.w = fmaxf(fmaf(v1.w, sc.w, sh.w), 0.f);
        }
        a0.x += v0.x; a0.y += v0.y; a0.z += v0.z; a0.w += v0.w;
        a1.x += v1.x; a1.y += v1.y; a1.z += v1.z; a1.w += v1.w;
    }
    if (i < end) {
        int s0 = eidx[i];
        float4 v0 = *reinterpret_cast<const float4*>(x + (size_t)s0 * F + f);
        if constexpr (AFF) {
            v0.x = fmaxf(fmaf(v0.x, sc.x, sh.x), 0.f);
            v0.y = fmaxf(fmaf(v0.y, sc.y, sh.y), 0.f);
            v0.z = fmaxf(fmaf(v0.z, sc.z, sh.z), 0.f);
            v0.w = fmaxf(fmaf(v0.w, sc.w, sh.w), 0.f);
        }
        a0.x += v0.x; a0.y += v0.y; a0.z += v0.z; a0.w += v0.w;
    }
    float4 acc = make_float4(a0.x + a1.x, a0.y + a1.y, a0.z + a1.z, a0.w + a1.w);
    float inv = 1.0f / (float)max(end - beg, 1);
    acc.x *= inv; acc.y *= inv; acc.z *= inv; acc.w *= inv;
    *reinterpret_cast<float4*>(agg + (size_t)node * F + f) = acc;
}

// Macro params renamed (A_/W_/S_) so none collides with the .x/.y/.z/.w member tokens.
#define FMA4(A_, W_, S_) { S_[0]=fmaf(A_,(W_).x,S_[0]); S_[1]=fmaf(A_,(W_).y,S_[1]); \
                           S_[2]=fmaf(A_,(W_).z,S_[2]); S_[3]=fmaf(A_,(W_).w,S_[3]); }

// ---------------- fused GEMM: y = agg@Wagg + bias + act(x)@Wroot, + BN col stats ----
// kk-blocked x4 inner loop: sX/sA read as ds_read_b128, 4 W rows held in regs.
// Grid: (ceil(M/ROWS), N/NB). Each block computes ROWS x NB output columns.
template<int K, int N, int NB, int ROWS, bool HAS_AGG, bool BN, bool AFFX>
__global__ __launch_bounds__(256, 4) void gemm_kernel(
    const float* __restrict__ xin, const float* __restrict__ agg,
    const float* __restrict__ Wroot, const float* __restrict__ Wagg,
    const float* __restrict__ bias, const float* __restrict__ ssx,
    float* __restrict__ y, float* __restrict__ stats, int M)
{
    constexpr int Kc  = 16;
    constexpr int CG  = NB / 4;         // col groups (threads in col dim)
    constexpr int RT  = 256 / CG;       // row threads
    constexpr int RPT = ROWS / RT;      // rows per thread
    constexpr int XP  = Kc + 4;         // padded LDS stride (20: 16B-aligned, breaks pow2)

    __shared__ float sWr[Kc * NB];
    __shared__ float sWa[HAS_AGG ? Kc * NB : 1];
    __shared__ float sX [ROWS * XP];
    __shared__ float sA [HAS_AGG ? ROWS * XP : 1];
    __shared__ float sStat[BN ? 2 * NB : 1];

    const int tid  = threadIdx.x;
    const int tx   = tid % CG;
    const int ty   = tid / CG;
    const int row0 = blockIdx.x * ROWS;
    const int col0 = blockIdx.y * NB;

    float acc[RPT][4];
    #pragma unroll
    for (int i = 0; i < RPT; i++) { acc[i][0]=0.f; acc[i][1]=0.f; acc[i][2]=0.f; acc[i][3]=0.f; }

    for (int k0 = 0; k0 < K; k0 += Kc) {
        // stage W chunk (Kc x NB) for both mats
        for (int idx = tid; idx < Kc * NB / 4; idx += 256) {
            int r = (idx * 4) / NB, c = (idx * 4) % NB;
            *reinterpret_cast<float4*>(&sWr[r * NB + c]) =
                *reinterpret_cast<const float4*>(&Wroot[(size_t)(k0 + r) * N + col0 + c]);
            if constexpr (HAS_AGG)
                *reinterpret_cast<float4*>(&sWa[r * NB + c]) =
                    *reinterpret_cast<const float4*>(&Wagg[(size_t)(k0 + r) * N + col0 + c]);
        }
        // stage x / agg tile (ROWS x Kc); apply producing-layer BN+ReLU to x if AFFX
        for (int idx = tid; idx < ROWS * Kc / 4; idx += 256) {
            int r = idx / (Kc / 4);
            int c = (idx % (Kc / 4)) * 4;
            int grow = row0 + r;
            float4 xv = make_float4(0.f, 0.f, 0.f, 0.f);
            float4 av = make_float4(0.f, 0.f, 0.f, 0.f);
            if (grow < M) {
                xv = *reinterpret_cast<const float4*>(&xin[(size_t)grow * K + k0 + c]);
                if constexpr (AFFX) {
                    float4 sc = *reinterpret_cast<const float4*>(&ssx[k0 + c]);
                    float4 sh = *reinterpret_cast<const float4*>(&ssx[K + k0 + c]);
                    xv.x = fmaxf(fmaf(xv.x, sc.x, sh.x), 0.f);
                    xv.y = fmaxf(fmaf(xv.y, sc.y, sh.y), 0.f);
                    xv.z = fmaxf(fmaf(xv.z, sc.z, sh.z), 0.f);
                    xv.w = fmaxf(fmaf(xv.w, sc.w, sh.w), 0.f);
                }
                if constexpr (HAS_AGG)
                    av = *reinterpret_cast<const float4*>(&agg[(size_t)grow * K + k0 + c]);
            }
            *reinterpret_cast<float4*>(&sX[r * XP + c]) = xv;
            if constexpr (HAS_AGG) *reinterpret_cast<float4*>(&sA[r * XP + c]) = av;
        }
        __syncthreads();

        #pragma unroll
        for (int kk0 = 0; kk0 < Kc; kk0 += 4) {
            float4 wr0 = *reinterpret_cast<const float4*>(&sWr[(kk0 + 0) * NB + tx * 4]);
            float4 wr1 = *reinterpret_cast<const float4*>(&sWr[(kk0 + 1) * NB + tx * 4]);
            float4 wr2 = *reinterpret_cast<const float4*>(&sWr[(kk0 + 2) * NB + tx * 4]);
            float4 wr3 = *reinterpret_cast<const float4*>(&sWr[(kk0 + 3) * NB + tx * 4]);
            float4 wa0, wa1, wa2, wa3;
            if constexpr (HAS_AGG) {
                wa0 = *reinterpret_cast<const float4*>(&sWa[(kk0 + 0) * NB + tx * 4]);
                wa1 = *reinterpret_cast<const float4*>(&sWa[(kk0 + 1) * NB + tx * 4]);
                wa2 = *reinterpret_cast<const float4*>(&sWa[(kk0 + 2) * NB + tx * 4]);
                wa3 = *reinterpret_cast<const float4*>(&sWa[(kk0 + 3) * NB + tx * 4]);
            }
            #pragma unroll
            for (int i = 0; i < RPT; i++) {
                int r = ty + i * RT;
                float4 xv = *reinterpret_cast<const float4*>(&sX[r * XP + kk0]);
                FMA4(xv.x, wr0, acc[i]);
                FMA4(xv.y, wr1, acc[i]);
                FMA4(xv.z, wr2, acc[i]);
                FMA4(xv.w, wr3, acc[i]);
                if constexpr (HAS_AGG) {
                    float4 av = *reinterpret_cast<const float4*>(&sA[r * XP + kk0]);
                    FMA4(av.x, wa0, acc[i]);
                    FMA4(av.y, wa1, acc[i]);
                    FMA4(av.z, wa2, acc[i]);
                    FMA4(av.w, wa3, acc[i]);
                }
            }
        }
        __syncthreads();
    }

    float4 bv = *reinterpret_cast<const float4*>(&bias[col0 + tx * 4]);

    if constexpr (BN) {
        for (int idx = tid; idx < 2 * NB; idx += 256) sStat[idx] = 0.f;
        __syncthreads();
    }

    float cs[4] = {0.f,0.f,0.f,0.f}, cq[4] = {0.f,0.f,0.f,0.f};
    #pragma unroll
    for (int i = 0; i < RPT; i++) {
        int grow = row0 + ty + i * RT;
        if (grow < M) {
            float4 o;
            o.x = acc[i][0] + bv.x;
            o.y = acc[i][1] + bv.y;
            o.z = acc[i][2] + bv.z;
            o.w = acc[i][3] + bv.w;
            *reinterpret_cast<float4*>(&y[(size_t)grow * N + col0 + tx * 4]) = o;
            if constexpr (BN) {
                cs[0] += o.x; cq[0] += o.x * o.x;
                cs[1] += o.y; cq[1] += o.y * o.y;
                cs[2] += o.z; cq[2] += o.z * o.z;
                cs[3] += o.w; cq[3] += o.w * o.w;
            }
        }
    }

    if constexpr (BN) {
        atomicAdd(&sStat[tx * 4 + 0], cs[0]);
        atomicAdd(&sStat[tx * 4 + 1], cs[1]);
        atomicAdd(&sStat[tx * 4 + 2], cs[2]);
        atomicAdd(&sStat[tx * 4 + 3], cs[3]);
        atomicAdd(&sStat[NB + tx * 4 + 0], cq[0]);
        atomicAdd(&sStat[NB + tx * 4 + 1], cq[1]);
        atomicAdd(&sStat[NB + tx * 4 + 2], cq[2]);
        atomicAdd(&sStat[NB + tx * 4 + 3], cq[3]);
        __syncthreads();
        for (int idx = tid; idx < 2 * NB; idx += 256) {
            int gidx = (idx < NB) ? (col0 + idx) : (N + col0 + idx - NB);
            unsafeAtomicAdd(&stats[gidx], sStat[idx]);
        }
    }
}

// ---------------- BN finalize: scale/shift per column ----------------
__global__ void bnfin_kernel(const float* __restrict__ stats, const float* __restrict__ g,
                             const float* __restrict__ be, float* __restrict__ ss,
                             int N, float invM) {
    int c = threadIdx.x;
    if (c >= N) return;
    float mean = stats[c] * invM;
    float var  = stats[N + c] * invM - mean * mean;
    float sc   = g[c] * rsqrtf(fmaxf(var, 0.f) + EPSV);
    ss[c]     = sc;
    ss[N + c] = be[c] - mean * sc;
}

extern "C" void kernel_launch(void* const* d_in, const int* in_sizes, int n_in,
                              void* d_out, int out_size, void* d_ws, size_t ws_size,
                              hipStream_t stream) {
    const float* x   = (const float*)d_in[0];
    const int*   ei  = (const int*)d_in[1];
    const int*   src = ei;
    const int*   dst = ei + NE;
    const float *W1l = (const float*)d_in[2],  *b1 = (const float*)d_in[3],
                *W1r = (const float*)d_in[4],  *g1 = (const float*)d_in[5],  *be1 = (const float*)d_in[6];
    const float *W2l = (const float*)d_in[7],  *b2 = (const float*)d_in[8],
                *W2r = (const float*)d_in[9],  *g2 = (const float*)d_in[10], *be2 = (const float*)d_in[11];
    const float *W3l = (const float*)d_in[12], *b3 = (const float*)d_in[13],
                *W3r = (const float*)d_in[14], *g3 = (const float*)d_in[15], *be3 = (const float*)d_in[16];
    const float *Wp  = (const float*)d_in[17], *bp = (const float*)d_in[18];

    char* w = (char*)d_ws;
    size_t off = 0;
    auto alloc = [&](size_t bytes) { char* p = w + off; off += (bytes + 255) & ~255ULL; return p; };

    int*   cnt     = (int*)  alloc(NNP * 4);          // zeroed
    float* stats   = (float*)alloc(1536 * 4);         // zeroed
    size_t zero_bytes = off;
    float* ss      = (float*)alloc(1536 * 4);
    int*   row_ptr = (int*)  alloc((NNP + 1) * 4);
    int*   fillc   = (int*)  alloc(NNP * 4);
    int*   bsum    = (int*)  alloc(256 * 4);
    int*   eidx    = (int*)  alloc((size_t)NE * 4);
    float* agg     = (float*)alloc((size_t)NN * 128 * 4);
    float* h1      = (float*)alloc((size_t)NN * 64 * 4);
    float* h2      = (float*)alloc((size_t)NN * 128 * 4);
    float* h3      = (float*)alloc((size_t)NN * 256 * 4);

    float* ss1 = ss + 0;     // [64 sc | 64 sh]
    float* ss2 = ss + 512;   // [128 sc | 128 sh]
    float* ss3 = ss + 1024;  // [256 sc | 256 sh]

    (void)hipMemsetAsync(d_ws, 0, zero_bytes, stream);

    // ---- CSR build (once, reused by all 3 layers) ----
    hist_kernel<<<(NE + 255) / 256, 256, 0, stream>>>(dst, cnt, NE);
    scan1_kernel<<<NNP / 256, 256, 0, stream>>>(cnt, row_ptr, bsum);
    scan2_kernel<<<1, 256, 0, stream>>>(bsum, NNP / 256);
    scan3_kernel<<<NNP / 256, 256, 0, stream>>>(row_ptr, bsum, fillc);
    fill_kernel<<<(NE + 255) / 256, 256, 0, stream>>>(src, dst, fillc, eidx, NE);

    // ---- layer 1: in 128 -> out 64 (raw x, no activation) ----
    gather_kernel<128, false><<<(NN * 32 + 255) / 256, 256, 0, stream>>>(
        x, row_ptr, eidx, agg, nullptr);
    gemm_kernel<128, 64, 64, 64, true, true, false>
        <<<dim3((NN + 63) / 64, 1), 256, 0, stream>>>(
        x, agg, W1r, W1l, b1, nullptr, h1, stats + 0, NN);
    bnfin_kernel<<<1, 256, 0, stream>>>(stats + 0, g1, be1, ss1, 64, 1.0f / NN);

    // ---- layer 2: in 64 -> out 128 (h1 activated on the fly via ss1) ----
    gather_kernel<64, true><<<(NN * 16 + 255) / 256, 256, 0, stream>>>(
        h1, row_ptr, eidx, agg, ss1);
    gemm_kernel<64, 128, 128, 64, true, true, true>
        <<<dim3((NN + 63) / 64, 1), 256, 0, stream>>>(
        h1, agg, W2r, W2l, b2, ss1, h2, stats + 512, NN);
    bnfin_kernel<<<1, 256, 0, stream>>>(stats + 512, g2, be2, ss2, 128, 1.0f / NN);

    // ---- layer 3: in 128 -> out 256 (h2 activated via ss2; N split over 2 blocks) ----
    gather_kernel<128, true><<<(NN * 32 + 255) / 256, 256, 0, stream>>>(
        h2, row_ptr, eidx, agg, ss2);
    gemm_kernel<128, 256, 128, 64, true, true, true>
        <<<dim3((NN + 63) / 64, 2), 256, 0, stream>>>(
        h2, agg, W3r, W3l, b3, ss2, h3, stats + 1024, NN);
    bnfin_kernel<<<1, 256, 0, stream>>>(stats + 1024, g3, be3, ss3, 256, 1.0f / NN);

    // ---- projection: 256 -> 128 (h3 activated via ss3), straight to d_out ----
    gemm_kernel<256, 128, 128, 64, false, false, true>
        <<<dim3((NN + 63) / 64, 1), 256, 0, stream>>>(
        h3, nullptr, Wp, nullptr, bp, ss3, (float*)d_out, nullptr, NN);
}